// Round 4
// baseline (406.861 us; speedup 1.0000x reference)
//
#include <hip/hip_runtime.h>
#include <hip/hip_bf16.h>
#include <math.h>

// ImageTokenization: conv3x3(64->64)+BN+GELU -> patches(masked) -> proj GEMM(2304->768)+GELU
// Inputs fp32, outputs fp32; compute bf16 MFMA. d_out = [tokens 8192x768][patches 8192x2304].
// R4: conv = raw-halo single-barrier implicit GEMM (B-frags from global); k_cvt fused into
// gemm staging; border-zero kernel replaces 39MB memset; gemm 128x128xBK64.

typedef unsigned short u16;
typedef __bf16 bf16x8 __attribute__((ext_vector_type(8)));
typedef float f32x4 __attribute__((ext_vector_type(4)));
typedef u16 u16x8 __attribute__((ext_vector_type(8)));

#define NFRM 32
#define CH 64
#define HW 96
#define HWP 98
#define KP 2304
#define DIMN 768
#define MTOK 8192
#define TOKN (MTOK * DIMN)
// ws layout (u16 units): [xhwc | bp | pw]  (~43 MB total)
#define XHWC_ELEMS ((size_t)NFRM * HWP * HWP * CH)
#define BP_OFF XHWC_ELEMS
#define PW_OFF (BP_OFF + 36864)

static __device__ __forceinline__ u16 f2b(float f) {
  unsigned u = __builtin_bit_cast(unsigned, f);
  u += 0x7fffu + ((u >> 16) & 1u);
  return (u16)(u >> 16);
}
static __device__ __forceinline__ float gelu_f(float x) {
  return 0.5f * x * (1.0f + erff(x * 0.7071067811865476f));
}

// -------- kernel 0: zero the 1-px halo border of xhwc (replaces full 39MB memset) --------
__global__ __launch_bounds__(256) void k_zero(u16* __restrict__ xhwc) {
  int id = blockIdx.x * 256 + threadIdx.x;  // exactly 388*256 = 32*388*8 chunks
  int p = id >> 3, cs = id & 7;
  int f = p / 388, bp = p - f * 388;
  int h, w;
  if (bp < 98) { h = 0; w = bp; }
  else if (bp < 196) { h = 97; w = bp - 98; }
  else { int q = bp - 196; h = 1 + (q >> 1); w = (q & 1) ? 97 : 0; }
  ushort4 z = {0, 0, 0, 0};
  *(ushort4*)(xhwc + ((size_t)(f * HWP + h) * HWP + w) * CH + cs * 8) = z;
}

// -------- kernel 1: x[32][64][96][96] fp32 -> xhwc[32][98][98][64] bf16 (interior) --------
__global__ __launch_bounds__(256) void k_transpose(const float* __restrict__ x,
                                                   u16* __restrict__ xhwc) {
  __shared__ u16 tile[96 * 66];
  const int f = blockIdx.x / 96, h = blockIdx.x % 96;
  const int t = threadIdx.x;
  const float* xp = x + (size_t)f * CH * HW * HW + (size_t)h * HW;
#pragma unroll
  for (int k = 0; k < 6; ++k) {
    int e = (k * 256 + t) * 4;
    int ci = e / 96, w = e % 96;
    float4 v = *(const float4*)(xp + (size_t)ci * (HW * HW) + w);
    tile[(w + 0) * 66 + ci] = f2b(v.x);
    tile[(w + 1) * 66 + ci] = f2b(v.y);
    tile[(w + 2) * 66 + ci] = f2b(v.z);
    tile[(w + 3) * 66 + ci] = f2b(v.w);
  }
  __syncthreads();
  u16* op = xhwc + ((size_t)(f * HWP + h + 1) * HWP + 1) * CH;
#pragma unroll
  for (int k = 0; k < 12; ++k) {
    int e2 = (k * 256 + t) * 2;
    int w = e2 >> 6, ci = e2 & 63;
    *(unsigned*)(op + e2) = *(const unsigned*)(&tile[w * 66 + ci]);
  }
}

// -------- kernel 2: conv_w[co][ci][3][3] fp32 -> bp[co][tap*64+ci] bf16 --------
__global__ __launch_bounds__(256) void k_bpack(const float* __restrict__ w,
                                               u16* __restrict__ bp) {
  int e = blockIdx.x * 256 + threadIdx.x;  // < 36864
  int co = e / 576, r = e - co * 576, tap = r >> 6, ci = r & 63;
  bp[e] = f2b(w[(co * 64 + ci) * 9 + tap]);
}

// -------- kernel 3: proj_w fp32 -> bf16 --------
__global__ __launch_bounds__(256) void k_pw(const float* __restrict__ pw,
                                            u16* __restrict__ dst) {
  int e = (blockIdx.x * 256 + threadIdx.x) * 4;  // < 1,769,472
  float4 v = *(const float4*)(pw + e);
  ushort4 o;
  o.x = f2b(v.x); o.y = f2b(v.y); o.z = f2b(v.z); o.w = f2b(v.w);
  *(ushort4*)(dst + e) = o;
}

// -------- kernel 4: conv via raw-halo LDS, single barrier --------
// Block: frame f, 2 pixel rows (h0,h0+1) x 96 w (M=192), all 64 co.
// LDS: raw input rows h0-1..h0+2 (xhwc rows h0..h0+3), width 98, ci padded to 72.
// A-frag for any tap = 8 contiguous ci at shifted pixel -> direct ds_read_b128.
// B-frags read per tap straight from global (bp is L1/L2 resident).
__global__ __launch_bounds__(256) void k_conv(
    const u16* __restrict__ xhwc, const u16* __restrict__ bw,
    const float* __restrict__ cb, const float* __restrict__ gma,
    const float* __restrict__ bta, const float* __restrict__ mu,
    const float* __restrict__ var, const float* __restrict__ msk,
    float* __restrict__ pout) {
  __shared__ u16 halo[4 * 98 * 72];  // 56.4 KB
  const int f = blockIdx.x / 48;
  const int h0 = (blockIdx.x % 48) * 2;
  const int t = threadIdx.x;
  const int wv = t >> 6, l = t & 63, quad = l >> 4, lm = l & 15;
  const u16* xf = xhwc + (size_t)f * (HWP * HWP * CH);

  // stage 4 rows x 98 px x 64 ci (16B chunks; 3136 chunks over 256 threads)
#pragma unroll
  for (int it = 0; it < 13; ++it) {
    int c = it * 256 + t;
    if (c < 3136) {
      int hr = c / 784, rem = c - hr * 784;
      int w = rem >> 3, cs = rem & 7;
      *(uint4*)(halo + (hr * 98 + w) * 72 + cs * 8) =
          *(const uint4*)(xf + ((size_t)(h0 + hr) * HWP + w) * CH + cs * 8);
    }
  }
  __syncthreads();  // the only barrier

  const int hr_out = wv >> 1;        // wave's output row within the pair
  const int wbase = (wv & 1) * 48;   // wave's w range: 48 px = 3 m-tiles

  f32x4 acc[3][4];
#pragma unroll
  for (int mt = 0; mt < 3; ++mt)
#pragma unroll
    for (int u = 0; u < 4; ++u) acc[mt][u] = (f32x4){0.f, 0.f, 0.f, 0.f};

#pragma unroll
  for (int tap = 0; tap < 9; ++tap) {
    const int di = tap / 3, dj = tap - di * 3;
    bf16x8 bfr[2][4];
#pragma unroll
    for (int ks = 0; ks < 2; ++ks)
#pragma unroll
      for (int u = 0; u < 4; ++u)
        bfr[ks][u] = *(const bf16x8*)(bw + (u * 16 + lm) * 576 + tap * 64 +
                                      ks * 32 + quad * 8);
#pragma unroll
    for (int mt = 0; mt < 3; ++mt) {
      const int base = ((hr_out + di) * 98 + wbase + mt * 16 + lm + dj) * 72;
#pragma unroll
      for (int ks = 0; ks < 2; ++ks) {
        bf16x8 a = *(const bf16x8*)(halo + base + ks * 32 + quad * 8);
#pragma unroll
        for (int u = 0; u < 4; ++u)
          acc[mt][u] =
              __builtin_amdgcn_mfma_f32_16x16x32_bf16(a, bfr[ks][u], acc[mt][u], 0, 0, 0);
      }
    }
  }

  // epilogue: BN + GELU + mask; store patch-ordered fp32
  const int hpx = h0 + hr_out;
  const int hd = hpx / 6, hm = hpx - hd * 6;
#pragma unroll
  for (int u = 0; u < 4; ++u) {
    const int co = u * 16 + lm;  // C/D col = lane&15
    const float scv = gma[co] * rsqrtf(var[co] + 1e-5f);
    const float b2v = (cb[co] - mu[co]) * scv + bta[co];
#pragma unroll
    for (int mt = 0; mt < 3; ++mt) {
#pragma unroll
      for (int rg = 0; rg < 4; ++rg) {
        const int wpx = wbase + mt * 16 + quad * 4 + rg;  // C/D row = quad*4+reg
        const int wd = wpx / 6, wm = wpx - wd * 6;
        const int np = hd * 16 + wd, ii = hm * 6 + wm;
        float v = acc[mt][u][rg] * scv + b2v;
        v = gelu_f(v) * msk[ii];
        pout[((size_t)(f * 256 + np) * 64 + co) * 36 + ii] = v;
      }
    }
  }
}

// -------- kernel 5: tokens = gelu(patches @ proj_w^T + proj_b) --------
// M=8192 K=2304 N=768; BM=128 BN=128 BK=64; A fp32 converted to bf16 in staging.
__global__ __launch_bounds__(256) void k_gemm(const float* __restrict__ A,
                                              const u16* __restrict__ Bt,
                                              const float* __restrict__ pb,
                                              float* __restrict__ out) {
  __shared__ u16 As[128 * 72];
  __shared__ u16 Bs[128 * 72];
  const int bm = blockIdx.x / 6, bn = blockIdx.x % 6;
  const int m0 = bm * 128, n0 = bn * 128;
  const int t = threadIdx.x, wv = t >> 6, l = t & 63, quad = l >> 4, lm = l & 15;
  const int wm = wv & 1, wn = wv >> 1;
  const int ar = t >> 1, half = (t & 1) * 32;

  f32x4 acc[4][4];
#pragma unroll
  for (int mt = 0; mt < 4; ++mt)
#pragma unroll
    for (int ut = 0; ut < 4; ++ut) acc[mt][ut] = (f32x4){0.f, 0.f, 0.f, 0.f};

  for (int k0 = 0; k0 < KP; k0 += 64) {
    __syncthreads();
    const float* asrc = A + (size_t)(m0 + ar) * KP + k0 + half;
    u16* adst = As + ar * 72 + half;
#pragma unroll
    for (int c = 0; c < 4; ++c) {
      float4 v0 = *(const float4*)(asrc + c * 8);
      float4 v1 = *(const float4*)(asrc + c * 8 + 4);
      u16x8 o;
      o[0] = f2b(v0.x); o[1] = f2b(v0.y); o[2] = f2b(v0.z); o[3] = f2b(v0.w);
      o[4] = f2b(v1.x); o[5] = f2b(v1.y); o[6] = f2b(v1.z); o[7] = f2b(v1.w);
      *(u16x8*)(adst + c * 8) = o;
    }
    const u16* bsrc = Bt + (size_t)(n0 + ar) * KP + k0 + half;
    u16* bdst = Bs + ar * 72 + half;
#pragma unroll
    for (int c = 0; c < 4; ++c)
      *(uint4*)(bdst + c * 8) = *(const uint4*)(bsrc + c * 8);
    __syncthreads();
#pragma unroll
    for (int ks = 0; ks < 2; ++ks) {
      bf16x8 af[4], bf[4];
#pragma unroll
      for (int mt = 0; mt < 4; ++mt)
        af[mt] = *(const bf16x8*)&As[(wm * 64 + mt * 16 + lm) * 72 + ks * 32 + quad * 8];
#pragma unroll
      for (int ut = 0; ut < 4; ++ut)
        bf[ut] = *(const bf16x8*)&Bs[(wn * 64 + ut * 16 + lm) * 72 + ks * 32 + quad * 8];
#pragma unroll
      for (int mt = 0; mt < 4; ++mt)
#pragma unroll
        for (int ut = 0; ut < 4; ++ut)
          acc[mt][ut] =
              __builtin_amdgcn_mfma_f32_16x16x32_bf16(af[mt], bf[ut], acc[mt][ut], 0, 0, 0);
    }
  }
#pragma unroll
  for (int ut = 0; ut < 4; ++ut) {
    const int n = n0 + wn * 64 + ut * 16 + lm;
    const float bias = pb[n];
#pragma unroll
    for (int mt = 0; mt < 4; ++mt)
#pragma unroll
      for (int rg = 0; rg < 4; ++rg) {
        const int m = m0 + wm * 64 + mt * 16 + quad * 4 + rg;
        out[(size_t)m * DIMN + n] = gelu_f(acc[mt][ut][rg] + bias);
      }
  }
}

extern "C" void kernel_launch(void* const* d_in, const int* in_sizes, int n_in,
                              void* d_out, int out_size, void* d_ws, size_t ws_size,
                              hipStream_t stream) {
  const float* x = (const float*)d_in[0];
  const float* conv_w = (const float*)d_in[1];
  const float* conv_b = (const float*)d_in[2];
  const float* bn_gamma = (const float*)d_in[3];
  const float* bn_beta = (const float*)d_in[4];
  const float* bn_mean = (const float*)d_in[5];
  const float* bn_var = (const float*)d_in[6];
  const float* proj_w = (const float*)d_in[7];
  const float* proj_b = (const float*)d_in[8];
  const float* mask = (const float*)d_in[9];
  float* out = (float*)d_out;
  float* patches = out + TOKN;
  u16* ws = (u16*)d_ws;
  u16* xhwc = ws;
  u16* bp = ws + BP_OFF;
  u16* pw = ws + PW_OFF;

  k_zero<<<388, 256, 0, stream>>>(xhwc);
  k_transpose<<<NFRM * HW, 256, 0, stream>>>(x, xhwc);
  k_bpack<<<144, 256, 0, stream>>>(conv_w, bp);
  k_pw<<<1728, 256, 0, stream>>>(proj_w, pw);
  k_conv<<<NFRM * 48, 256, 0, stream>>>(xhwc, bp, conv_b, bn_gamma, bn_beta,
                                        bn_mean, bn_var, mask, patches);
  k_gemm<<<64 * 6, 256, 0, stream>>>(patches, pw, proj_b, out);
}